// Round 5
// baseline (842.756 us; speedup 1.0000x reference)
//
#include <hip/hip_runtime.h>
#include <hip/hip_bf16.h>
#include <math.h>

// ---------------------------------------------------------------------------
// S2ConvNetModified pipeline.
// Round 5: GEMM1/GEMM2 with NO LDS — MFMA fragments loaded directly from
// global (L2/L3-resident bf16) into registers, 2-deep register double-buffer,
// no barriers. LDS-pipe serialization was the v3/v4 ~155 µs plateau.
// ---------------------------------------------------------------------------

#define B_      32
#define F1_     20
#define F2_     40
#define NC1     1771
#define K1P     1792          // NC1 padded to multiple of 32
#define NG1     32000
#define NC2     286
#define K2P     288           // NC2 padded to multiple of 32
#define NG2     6912
#define SQRT2_  1.41421356237309515f
#define RS24    0.20412414523193154f   // 1/sqrt(24)
#define RS168   0.07715167498104595f   // 1/sqrt(168)

typedef unsigned int   uint32;
typedef unsigned short u16;
typedef __attribute__((ext_vector_type(8))) short short8;
typedef __attribute__((ext_vector_type(4))) float f32x4;

#define AS1(p) ((const __attribute__((address_space(1))) void*)(p))
#define AS3(p) ((__attribute__((address_space(3))) void*)(p))

__device__ __forceinline__ u16 f2bf(float f) {            // RNE f32 -> bf16 bits
  uint32 u = __float_as_uint(f);
  return (u16)((u + 0x7FFFu + ((u >> 16) & 1u)) >> 16);
}
__device__ __forceinline__ uint32 pack_bf16(float lo, float hi) {
  uint32 a = __float_as_uint(lo), b = __float_as_uint(hi);
  a = (a + 0x7FFFu + ((a >> 16) & 1u)) >> 16;
  b = (b + 0x7FFFu + ((b >> 16) & 1u)) & 0xFFFF0000u;
  return a | b;
}

__device__ __forceinline__ float wave_reduce(float v) {
#pragma unroll
  for (int o = 32; o > 0; o >>= 1) v += __shfl_down(v, o, 64);
  return v;
}

// ------------------------- small prologue kernels --------------------------

// x [32,96,96] -> x_t [32, 9216] with x_t[b, j*96+i] = x[b, i*96+j]
__global__ void k_xt(const float* __restrict__ x, float* __restrict__ xt) {
  __shared__ float t[32][33];
  const int b = blockIdx.z, i0 = blockIdx.x * 32, j0 = blockIdx.y * 32;
  const int tx = threadIdx.x & 31, ty0 = threadIdx.x >> 5;
  const float* xb = x + b * 9216;
  float* xtb = xt + b * 9216;
#pragma unroll
  for (int r = 0; r < 4; ++r) {
    const int ty = ty0 + r * 8;
    t[ty][tx] = xb[(i0 + ty) * 96 + j0 + tx];
  }
  __syncthreads();
#pragma unroll
  for (int r = 0; r < 4; ++r) {
    const int ty = ty0 + r * 8;
    xtb[(j0 + ty) * 96 + i0 + tx] = t[tx][ty];
  }
}

// c[b,ch] = sum_g x_t[b,g] * from_s2[ch,g]  (coalesced float4)
__global__ void k_c2(const float* __restrict__ xt, const float* __restrict__ fs,
                     float* __restrict__ c) {
  const int ch = blockIdx.x, b = blockIdx.y, tid = threadIdx.x;
  const float4* xb = (const float4*)(xt + b * 9216);
  const float4* fr = (const float4*)(fs + ch * 9216);
  float s = 0.f;
#pragma unroll 3
  for (int g = tid; g < 2304; g += 256) {
    const float4 a = xb[g], d = fr[g];
    s += a.x * d.x + a.y * d.y + a.z * d.z + a.w * d.w;
  }
  s = wave_reduce(s);
  __shared__ float red[4];
  if ((tid & 63) == 0) red[tid >> 6] = s;
  __syncthreads();
  if (tid == 0) c[b * 121 + ch] = red[0] + red[1] + red[2] + red[3];
}

// fallback (uncoalesced) k_c
__global__ void k_c(const float* __restrict__ x, const float* __restrict__ fs,
                    float* __restrict__ c) {
  const int ch = blockIdx.x, b = blockIdx.y, tid = threadIdx.x;
  const float* xb = x + b * 9216;
  const float* fr = fs + ch * 9216;
  float s = 0.f;
  for (int g = tid; g < 9216; g += 256) {
    s += xb[(g % 96) * 96 + (g / 96)] * fr[g];
  }
  s = wave_reduce(s);
  __shared__ float red[4];
  if ((tid & 63) == 0) red[tid >> 6] = s;
  __syncthreads();
  if (tid == 0) c[b * 121 + ch] = red[0] + red[1] + red[2] + red[3];
}

__global__ void k_psi1(const float* __restrict__ Yk1, const float* __restrict__ w1,
                       float* __restrict__ psi1) {
  const int j = blockIdx.x, i = threadIdx.x;
  __shared__ float wsm[24];
  if (i < 24) wsm[i] = w1[j * 24 + i];
  __syncthreads();
  if (i < 121) {
    float s = 0.f;
#pragma unroll
    for (int n = 0; n < 24; ++n) s += Yk1[n * 121 + i] * wsm[n];
    psi1[j * 121 + i] = s * RS24;
  }
}

__global__ void k_h(const float* __restrict__ c, const float* __restrict__ psi1,
                    u16* __restrict__ hb) {
  const int j = blockIdx.x, b = blockIdx.y, tid = threadIdx.x;
  __shared__ float cs[121], ps[121];
  if (tid < 121) { cs[tid] = c[b * 121 + tid]; ps[tid] = psi1[j * 121 + tid]; }
  __syncthreads();
  for (int idx = tid; idx < K1P; idx += 256) {
    u16 v = 0;
    if (idx < NC1) {
      int off = 0, l = 0, k = 1;
      while (idx >= off + k * k) { off += k * k; ++l; k += 2; }
      const int r = idx - off, n = r / k, m = r % k;
      v = f2bf(cs[l * l + m] * ps[l * l + n]);
    }
    hb[(size_t)(b * F1_ + j) * K1P + idx] = v;
  }
}

// ------------------------- bf16 convert kernels ----------------------------

__global__ void k_cvt1(const float* __restrict__ in, uint32* __restrict__ out) {
  const int total = 32000 * 896;
  for (int id = blockIdx.x * 256 + threadIdx.x; id < total; id += gridDim.x * 256) {
    const int r = id / 896, c2 = id % 896, cc = c2 * 2;
    const float* p = in + (size_t)r * NC1 + cc;
    const float lo = (cc < NC1) ? p[0] : 0.f;
    const float hi = (cc + 1 < NC1) ? p[1] : 0.f;
    out[id] = pack_bf16(lo, hi);
  }
}

__global__ void k_cvt2(const float* __restrict__ in, uint32* __restrict__ out) {
  const int total = 286 * 16000;
  for (int id = blockIdx.x * 256 + threadIdx.x; id < total; id += gridDim.x * 256) {
    out[id] = pack_bf16(in[2 * id], in[2 * id + 1]);
  }
}

__global__ void k_cvt3(const float* __restrict__ in, uint32* __restrict__ out) {
  const int total = 6912 * 144;
  for (int id = blockIdx.x * 256 + threadIdx.x; id < total; id += gridDim.x * 256) {
    const int r = id / 144, c2 = id % 144, cc = c2 * 2;
    const float* p = in + (size_t)r * NC2 + cc;
    const float lo = (cc < NC2) ? p[0] : 0.f;
    const float hi = (cc + 1 < NC2) ? p[1] : 0.f;
    out[id] = pack_bf16(lo, hi);
  }
}

// ------------------- GEMM1 v5: no-LDS direct-register MFMA -----------------
// g[m,n] = bf16( sqrt(2)*relu( sum_k hb[m,k] * D1bf[n,k] ) )
// M=640, N=32000, K=1792. Block = 4 waves (2x2), each wave a 64x64 tile.
// Fragments loaded straight from global: lane(q,r16) reads 16 B at
// row(r16)*ldK + k + q*8 (16 fully-used 64B lines per load instr).

#define MFMA16(ab, bb)                                                          \
  {                                                                             \
    _Pragma("unroll")                                                           \
    for (int mb = 0; mb < 4; ++mb)                                              \
      _Pragma("unroll")                                                         \
      for (int nb = 0; nb < 4; ++nb)                                            \
        acc[mb][nb] = __builtin_amdgcn_mfma_f32_16x16x32_bf16((ab)[mb], (bb)[nb], \
                                                              acc[mb][nb], 0, 0, 0); \
  }

#define LD8(ab, bb, kc)                                                         \
  {                                                                             \
    _Pragma("unroll")                                                           \
    for (int mb = 0; mb < 4; ++mb) (ab)[mb] = *(const short8*)(ap[mb] + (kc) * 32); \
    _Pragma("unroll")                                                           \
    for (int nb = 0; nb < 4; ++nb) (bb)[nb] = *(const short8*)(bp[nb] + (kc) * 32); \
  }

__launch_bounds__(256, 3)
__global__ void k_gemm1_v5(const u16* __restrict__ A, const u16* __restrict__ B,
                           u16* __restrict__ C) {
  const int bid = blockIdx.x;                // 0..1249, XCD swizzle
  const int gg = bid / 40, loc = bid % 40;
  int nt, mt;
  if (gg < 31) { nt = gg * 8 + (loc & 7); mt = loc >> 3; }
  else         { nt = 248 + (loc & 1);   mt = loc >> 1; }
  const int m0 = mt * 128, n0 = nt * 128;
  const int tid = threadIdx.x;
  const int lane = tid & 63, w = tid >> 6;
  const int wm = w >> 1, wn = w & 1;
  const int q = lane >> 4, r16 = lane & 15;

  const u16* ap[4];
  const u16* bp[4];
#pragma unroll
  for (int mb = 0; mb < 4; ++mb)
    ap[mb] = A + (size_t)(m0 + wm * 64 + mb * 16 + r16) * K1P + q * 8;
#pragma unroll
  for (int nb = 0; nb < 4; ++nb)
    bp[nb] = B + (size_t)(n0 + wn * 64 + nb * 16 + r16) * K1P + q * 8;

  f32x4 acc[4][4] = {};
  short8 a0[4], b0[4], a1[4], b1[4];
  LD8(a0, b0, 0)
  LD8(a1, b1, 1)
  for (int kc = 0; kc < 54; kc += 2) {      // K1P/32 = 56 iters total
    MFMA16(a0, b0)
    LD8(a0, b0, kc + 2)
    MFMA16(a1, b1)
    LD8(a1, b1, kc + 3)
  }
  MFMA16(a0, b0)
  MFMA16(a1, b1)

#pragma unroll
  for (int mb = 0; mb < 4; ++mb) {
#pragma unroll
    for (int nb = 0; nb < 4; ++nb) {
      const int col = n0 + wn * 64 + nb * 16 + r16;
#pragma unroll
      for (int r = 0; r < 4; ++r) {
        const int row = m0 + wm * 64 + mb * 16 + q * 4 + r;
        float v = acc[mb][nb][r];
        v = (v > 0.f) ? v * SQRT2_ : 0.f;
        C[(size_t)row * NG1 + col] = f2bf(v);
      }
    }
  }
}

// ------------------- GEMM2 v5: no-LDS, split-K=25 --------------------------
// h2[m,n] += sum_k g[m,k] * F1bf[n,k]; M=640, N=286, K=32000 -> 25 x 1280.
__launch_bounds__(256, 3)
__global__ void k_gemm2_v5(const u16* __restrict__ A, const u16* __restrict__ B,
                           float* __restrict__ C) {
  const int m0 = blockIdx.x * 128, n0 = blockIdx.y * 128;
  const int ksc = blockIdx.z * 40;           // kc base (32-elem units)
  const int tid = threadIdx.x;
  const int lane = tid & 63, w = tid >> 6;
  const int wm = w >> 1, wn = w & 1;
  const int q = lane >> 4, r16 = lane & 15;

  const u16* ap[4];
  const u16* bp[4];
#pragma unroll
  for (int mb = 0; mb < 4; ++mb)
    ap[mb] = A + (size_t)(m0 + wm * 64 + mb * 16 + r16) * NG1 + (size_t)ksc * 32 + q * 8;
#pragma unroll
  for (int nb = 0; nb < 4; ++nb) {
    int rr = n0 + wn * 64 + nb * 16 + r16;
    if (rr > 285) rr = 285;                 // clamp; masked at store
    bp[nb] = B + (size_t)rr * NG1 + (size_t)ksc * 32 + q * 8;
  }

  f32x4 acc[4][4] = {};
  short8 a0[4], b0[4], a1[4], b1[4];
  LD8(a0, b0, 0)
  LD8(a1, b1, 1)
  for (int kc = 0; kc < 38; kc += 2) {      // 40 iters total
    MFMA16(a0, b0)
    LD8(a0, b0, kc + 2)
    MFMA16(a1, b1)
    LD8(a1, b1, kc + 3)
  }
  MFMA16(a0, b0)
  MFMA16(a1, b1)

#pragma unroll
  for (int mb = 0; mb < 4; ++mb) {
#pragma unroll
    for (int nb = 0; nb < 4; ++nb) {
      const int col = n0 + wn * 64 + nb * 16 + r16;
      if (col < NC2) {
#pragma unroll
        for (int r = 0; r < 4; ++r) {
          const int row = m0 + wm * 64 + mb * 16 + q * 4 + r;
          atomicAdd(&C[(size_t)row * NC2 + col], acc[mb][nb][r]);
        }
      }
    }
  }
}

// GEMM3 fused epilogue (LDS version, 9 iters — cheap):
// out[m] += sqrt(2)*sum_n relu(sum_k h3b[m,k]*D2bf[n,k])*F2_from[n]
__launch_bounds__(256)
__global__ void k_gemm3_v3(const u16* __restrict__ A, const u16* __restrict__ B,
                           const float* __restrict__ wv, float* __restrict__ out) {
  __shared__ __align__(16) u16 As[128 * 32];
  __shared__ __align__(16) u16 Bs[128 * 32];
  __shared__ float red[128][33];
  const int m0 = blockIdx.x * 128, n0 = blockIdx.y * 128;
  const int tid = threadIdx.x;
  const int lane = tid & 63, w = tid >> 6;
  const int wm = w >> 1, wn = w & 1;
  const int q = lane >> 4, r16 = lane & 15;

  f32x4 acc[4][4] = {};
  const u16* ag = A + (size_t)(m0 + (tid >> 2)) * K2P + (tid & 3) * 8;
  const u16* bg = B + (size_t)(n0 + (tid >> 2)) * K2P + (tid & 3) * 8;

  for (int k0 = 0; k0 < K2P; k0 += 32) {
#pragma unroll
    for (int i = 0; i < 2; ++i) {
      __builtin_amdgcn_global_load_lds(AS1(ag + k0 + (size_t)i * 64 * K2P),
                                       AS3((char*)As + i * 4096 + w * 1024), 16, 0, 0);
      __builtin_amdgcn_global_load_lds(AS1(bg + k0 + (size_t)i * 64 * K2P),
                                       AS3((char*)Bs + i * 4096 + w * 1024), 16, 0, 0);
    }
    __syncthreads();
    short8 af[4], bq[4];
#pragma unroll
    for (int mb = 0; mb < 4; ++mb)
      af[mb] = *(const short8*)&As[(wm * 64 + mb * 16 + r16) * 32 + q * 8];
#pragma unroll
    for (int nb = 0; nb < 4; ++nb)
      bq[nb] = *(const short8*)&Bs[(wn * 64 + nb * 16 + r16) * 32 + q * 8];
#pragma unroll
    for (int mb = 0; mb < 4; ++mb)
#pragma unroll
      for (int nb = 0; nb < 4; ++nb)
        acc[mb][nb] = __builtin_amdgcn_mfma_f32_16x16x32_bf16(af[mb], bq[nb], acc[mb][nb], 0, 0, 0);
    __syncthreads();
  }
  float wvv[4];
#pragma unroll
  for (int nb = 0; nb < 4; ++nb) wvv[nb] = wv[n0 + wn * 64 + nb * 16 + r16];
#pragma unroll
  for (int mb = 0; mb < 4; ++mb) {
#pragma unroll
    for (int r = 0; r < 4; ++r) {
      const int rowl = wm * 64 + mb * 16 + q * 4 + r;
      float t = 0.f;
#pragma unroll
      for (int nb = 0; nb < 4; ++nb) {
        float v = acc[mb][nb][r];
        v = (v > 0.f) ? v : 0.f;
        t += v * wvv[nb];
      }
      red[rowl][wn * 16 + r16] = t;
    }
  }
  __syncthreads();
  if (tid < 128) {
    float s = 0.f;
#pragma unroll
    for (int cc = 0; cc < 32; ++cc) s += red[tid][cc];
    atomicAdd(&out[m0 + tid], s * SQRT2_);
  }
}

// ------------------- fallback GEMM1/GEMM2 (on-the-fly cvt) -----------------

__launch_bounds__(256)
__global__ void k_gemm1_mfma(const u16* __restrict__ A, const float* __restrict__ Bf,
                             u16* __restrict__ C) {
  __shared__ __align__(16) u16 As[128 * 32];
  __shared__ __align__(16) u16 Bs[128 * 32];
  const int tid = threadIdx.x;
  const int lane = tid & 63, w = tid >> 6;
  const int wm = w >> 1, wn = w & 1;
  const int q = lane >> 4, r16 = lane & 15;
  const int m0 = blockIdx.x * 128, n0 = blockIdx.y * 128;

  f32x4 acc[4][4] = {};
  const u16* ag = A + (size_t)(m0 + (tid >> 2)) * K1P + (tid & 3) * 8;

  for (int k0 = 0; k0 < K1P; k0 += 32) {
#pragma unroll
    for (int i = 0; i < 2; ++i) {
      __builtin_amdgcn_global_load_lds(AS1(ag + k0 + (size_t)i * 64 * K1P),
                                       AS3((char*)As + i * 4096 + w * 1024), 16, 0, 0);
    }
#pragma unroll
    for (int i = 0; i < 8; ++i) {
      const int p = i * 256 + tid;
      const int row = p >> 4, c2 = (p & 15) * 2;
      const int kk = k0 + c2;
      const float* bpp = Bf + (size_t)(n0 + row) * NC1 + kk;
      const float lo = (kk < NC1) ? bpp[0] : 0.f;
      const float hi = (kk + 1 < NC1) ? bpp[1] : 0.f;
      ((uint32*)Bs)[row * 16 + (p & 15)] = pack_bf16(lo, hi);
    }
    __syncthreads();
    short8 af[4], bq[4];
#pragma unroll
    for (int mb = 0; mb < 4; ++mb)
      af[mb] = *(const short8*)&As[(wm * 64 + mb * 16 + r16) * 32 + q * 8];
#pragma unroll
    for (int nb = 0; nb < 4; ++nb)
      bq[nb] = *(const short8*)&Bs[(wn * 64 + nb * 16 + r16) * 32 + q * 8];
#pragma unroll
    for (int mb = 0; mb < 4; ++mb)
#pragma unroll
      for (int nb = 0; nb < 4; ++nb)
        acc[mb][nb] = __builtin_amdgcn_mfma_f32_16x16x32_bf16(af[mb], bq[nb], acc[mb][nb], 0, 0, 0);
    __syncthreads();
  }
#pragma unroll
  for (int mb = 0; mb < 4; ++mb) {
#pragma unroll
    for (int nb = 0; nb < 4; ++nb) {
      const int col = n0 + wn * 64 + nb * 16 + r16;
#pragma unroll
      for (int r = 0; r < 4; ++r) {
        const int row = m0 + wm * 64 + mb * 16 + q * 4 + r;
        float v = acc[mb][nb][r];
        v = (v > 0.f) ? v * SQRT2_ : 0.f;
        C[(size_t)row * NG1 + col] = f2bf(v);
      }
    }
  }
}

__launch_bounds__(256)
__global__ void k_gemm2_mfma(const u16* __restrict__ A, const float* __restrict__ Bf,
                             float* __restrict__ C) {
  __shared__ __align__(16) u16 As[128 * 32];
  __shared__ __align__(16) u16 Bs[128 * 32];
  const int tid = threadIdx.x;
  const int lane = tid & 63, w = tid >> 6;
  const int wm = w >> 1, wn = w & 1;
  const int q = lane >> 4, r16 = lane & 15;
  const int m0 = blockIdx.x * 128, n0 = blockIdx.y * 128;
  const int ks = blockIdx.z * 1600;

  f32x4 acc[4][4] = {};
  const u16* ag = A + (size_t)(m0 + (tid >> 2)) * NG1 + ks + (tid & 3) * 8;

  for (int kt = 0; kt < 1600; kt += 32) {
#pragma unroll
    for (int i = 0; i < 2; ++i) {
      __builtin_amdgcn_global_load_lds(AS1(ag + kt + (size_t)i * 64 * NG1),
                                       AS3((char*)As + i * 4096 + w * 1024), 16, 0, 0);
    }
#pragma unroll
    for (int i = 0; i < 4; ++i) {
      const int idx = i * 256 + tid;
      const int row = idx >> 3, c4 = (idx & 7) * 4;
      const int n = n0 + row;
      float4 v = make_float4(0.f, 0.f, 0.f, 0.f);
      if (n < NC2) v = *(const float4*)(Bf + (size_t)n * NG1 + ks + kt + c4);
      ((uint32*)Bs)[row * 16 + (idx & 7) * 2]     = pack_bf16(v.x, v.y);
      ((uint32*)Bs)[row * 16 + (idx & 7) * 2 + 1] = pack_bf16(v.z, v.w);
    }
    __syncthreads();
    short8 af[4], bq[4];
#pragma unroll
    for (int mb = 0; mb < 4; ++mb)
      af[mb] = *(const short8*)&As[(wm * 64 + mb * 16 + r16) * 32 + q * 8];
#pragma unroll
    for (int nb = 0; nb < 4; ++nb)
      bq[nb] = *(const short8*)&Bs[(wn * 64 + nb * 16 + r16) * 32 + q * 8];
#pragma unroll
    for (int mb = 0; mb < 4; ++mb)
#pragma unroll
      for (int nb = 0; nb < 4; ++nb)
        acc[mb][nb] = __builtin_amdgcn_mfma_f32_16x16x32_bf16(af[mb], bq[nb], acc[mb][nb], 0, 0, 0);
    __syncthreads();
  }
#pragma unroll
  for (int mb = 0; mb < 4; ++mb) {
#pragma unroll
    for (int nb = 0; nb < 4; ++nb) {
      const int col = n0 + wn * 64 + nb * 16 + r16;
      if (col < NC2) {
#pragma unroll
        for (int r = 0; r < 4; ++r) {
          const int row = m0 + wm * 64 + mb * 16 + q * 4 + r;
          atomicAdd(&C[(size_t)row * NC2 + col], acc[mb][nb][r]);
        }
      }
    }
  }
}

// ------------------------- mid/tail kernels --------------------------------

__global__ void k_psi2(const float* __restrict__ Dk2, const float* __restrict__ w2,
                       float* __restrict__ psi2) {
  const int blk = blockIdx.x, tid = threadIdx.x;   // blk = i*40+j
  __shared__ float w2s[168];
  if (tid < 168) w2s[tid] = w2[blk * 168 + tid];
  __syncthreads();
  for (int cc = tid; cc < NC2; cc += 256) {
    float s = 0.f;
    for (int n = 0; n < 168; ++n) s += Dk2[n * NC2 + cc] * w2s[n];
    psi2[blk * NC2 + cc] = s * RS168;
  }
}

__global__ void k_step7(const float* __restrict__ h2, const float* __restrict__ psi2,
                        u16* __restrict__ h3b) {
  const int j = blockIdx.x, b = blockIdx.y, tid = threadIdx.x;
  __shared__ float sh[20 * 286];
  __shared__ float sp[20 * 286];
  for (int e = tid; e < 20 * 286; e += 256) {
    const int i = e / 286, cc = e % 286;
    sh[e] = h2[(b * F1_ + i) * NC2 + cc];
    sp[e] = psi2[(i * F2_ + j) * NC2 + cc];
  }
  __syncthreads();
  for (int cidx = tid; cidx < K2P; cidx += 256) {
    u16 ov = 0;
    if (cidx < NC2) {
      int off = 0, l = 0, k = 1;
      while (cidx >= off + k * k) { off += k * k; ++l; k += 2; }
      const int r = cidx - off, v = r / k, m = r % k;
      float acc = 0.f;
      for (int i = 0; i < 20; ++i) {
        const float* hbp = &sh[i * 286 + off];
        const float* pb = &sp[i * 286 + off];
        for (int u = 0; u < k; ++u) acc += hbp[u * k + m] * pb[u * k + v];
      }
      ov = f2bf(acc * rsqrtf(20.f * (float)k));
    }
    h3b[(size_t)(b * F2_ + j) * K2P + cidx] = ov;
  }
}

// ------------------------------- launcher ----------------------------------

extern "C" void kernel_launch(void* const* d_in, const int* in_sizes, int n_in,
                              void* d_out, int out_size, void* d_ws, size_t ws_size,
                              hipStream_t stream) {
  const float* x       = (const float*)d_in[0];
  const float* w1      = (const float*)d_in[1];
  const float* w2      = (const float*)d_in[2];
  const float* Yk1     = (const float*)d_in[3];
  const float* Dk2     = (const float*)d_in[4];
  const float* from_s2 = (const float*)d_in[5];
  const float* D1_to   = (const float*)d_in[6];
  const float* F1_from = (const float*)d_in[7];
  const float* D2_to   = (const float*)d_in[8];
  const float* F2_from = (const float*)d_in[9];
  float* out = (float*)d_out;

  float* ws = (float*)d_ws;
  float* c    = ws + 0;            //   3,872
  float* psi1 = ws + 3872;         //   2,420
  float* h2   = ws + 6292;         // 183,040
  float* psi2 = ws + 189332;       // 228,800
  u16*   h3b  = (u16*)(ws + 418132);      // 1280*288 u16  = 184,320 f
  u16*   hb   = (u16*)(ws + 602452);      // 640*1792 u16  = 573,440 f
  u16*   g    = (u16*)(ws + 1175892);     // 640*32000 u16 = 10,240,000 f
  u16*   D2bf = (u16*)(ws + 11415892);    // 6912*288 u16  = 995,328 f
  u16*   F1bf = (u16*)(ws + 12411220);    // 286*32000 u16 = 4,576,000 f
  u16*   D1bf = (u16*)(ws + 16987220);    // 32000*1792 u16= 28,672,000 f
  float* x_t  = ws + 45659220;            // 32*9216       = 294,912 f
  const size_t BIG_NEED = (size_t)45659220 * 4;   // ~182.6 MB (proven OK R3/R4)
  const size_t XT_NEED  = (size_t)45954132 * 4;   // +x_t
  const bool big   = ws_size >= BIG_NEED;
  const bool useXT = ws_size >= XT_NEED;

  if (useXT) {
    k_xt<<<dim3(3, 3, 32), 256, 0, stream>>>(x, x_t);
    k_c2<<<dim3(121, 32),  256, 0, stream>>>(x_t, from_s2, c);
  } else {
    k_c <<<dim3(121, 32),  256, 0, stream>>>(x, from_s2, c);
  }
  k_psi1<<<dim3(20),      128, 0, stream>>>(Yk1, w1, psi1);
  k_h   <<<dim3(20, 32),  256, 0, stream>>>(c, psi1, hb);
  k_cvt3<<<dim3(1024),    256, 0, stream>>>(D2_to, (uint32*)D2bf);

  if (big) {
    k_cvt1<<<dim3(8192), 256, 0, stream>>>(D1_to, (uint32*)D1bf);
    k_cvt2<<<dim3(4096), 256, 0, stream>>>(F1_from, (uint32*)F1bf);
    k_gemm1_v5<<<dim3(1250), 256, 0, stream>>>(hb, D1bf, g);
    hipMemsetAsync(h2, 0, (size_t)640 * 286 * sizeof(float), stream);
    k_gemm2_v5<<<dim3(5, 3, 25), 256, 0, stream>>>(g, F1bf, h2);
  } else {
    k_gemm1_mfma<<<dim3(5, 250), 256, 0, stream>>>(hb, D1_to, g);
    hipMemsetAsync(h2, 0, (size_t)640 * 286 * sizeof(float), stream);
    k_gemm2_mfma<<<dim3(5, 3, 20), 256, 0, stream>>>(g, F1_from, h2);
  }

  k_psi2 <<<dim3(800),    256, 0, stream>>>(Dk2, w2, psi2);
  k_step7<<<dim3(40, 32), 256, 0, stream>>>(h2, psi2, h3b);

  hipMemsetAsync(out, 0, (size_t)1280 * sizeof(float), stream);
  k_gemm3_v3<<<dim3(10, 54), 256, 0, stream>>>(h3b, D2bf, F2_from, out);
}

// Round 6
// 676.804 us; speedup vs baseline: 1.2452x; 1.2452x over previous
//
#include <hip/hip_runtime.h>
#include <hip/hip_bf16.h>
#include <math.h>

// ---------------------------------------------------------------------------
// S2ConvNetModified pipeline.
// Round 6: (a) revert no-LDS experiment; gemm1_v6 = triple-buffered LDS MFMA
// with 2-wave blocks, wave tile 64x128 (12 ds_read per 32 MFMA, was 8/16) and
// corrected final vmcnt drain. (b) merge all independent prologue kernels
// into one k_prep dispatch (7 dispatches total, no memsets).
// ---------------------------------------------------------------------------

#define B_      32
#define F1_     20
#define F2_     40
#define NC1     1771
#define K1P     1792          // NC1 padded to multiple of 32
#define NG1     32000
#define NC2     286
#define K2P     288           // NC2 padded to multiple of 32
#define NG2     6912
#define SQRT2_  1.41421356237309515f
#define RS24    0.20412414523193154f   // 1/sqrt(24)
#define RS168   0.07715167498104595f   // 1/sqrt(168)

typedef unsigned int   uint32;
typedef unsigned short u16;
typedef __attribute__((ext_vector_type(8))) short short8;
typedef __attribute__((ext_vector_type(4))) float f32x4;

#define AS1(p) ((const __attribute__((address_space(1))) void*)(p))
#define AS3(p) ((__attribute__((address_space(3))) void*)(p))

// s_waitcnt imm: lgkmcnt=0xF (no wait), expcnt=7 (no wait), vmcnt=N
#define WAITCNT_VM8 0x0F78
#define WAITCNT_VM0 0x0F70

__device__ __forceinline__ u16 f2bf(float f) {            // RNE f32 -> bf16 bits
  uint32 u = __float_as_uint(f);
  return (u16)((u + 0x7FFFu + ((u >> 16) & 1u)) >> 16);
}
__device__ __forceinline__ uint32 pack_bf16(float lo, float hi) {
  uint32 a = __float_as_uint(lo), b = __float_as_uint(hi);
  a = (a + 0x7FFFu + ((a >> 16) & 1u)) >> 16;
  b = (b + 0x7FFFu + ((b >> 16) & 1u)) & 0xFFFF0000u;
  return a | b;
}

__device__ __forceinline__ float wave_reduce(float v) {
#pragma unroll
  for (int o = 32; o > 0; o >>= 1) v += __shfl_down(v, o, 64);
  return v;
}

// ------------------- k_prep: all independent prologue work -----------------
// regions: [0,8192) cvt1 | [,+2048) cvt2 | [,+512) cvt3 | [,+800) psi2 |
//          [,+288) x-transpose | [,+20) psi1 | [,+184) zero h2+out
#define PREP_BLOCKS (8192 + 2048 + 512 + 800 + 288 + 20 + 184)

__global__ void k_prep(const float* __restrict__ D1, const float* __restrict__ F1,
                       const float* __restrict__ D2, const float* __restrict__ Yk1,
                       const float* __restrict__ w1, const float* __restrict__ Dk2,
                       const float* __restrict__ w2, const float* __restrict__ x,
                       uint32* __restrict__ D1bf, uint32* __restrict__ F1bf,
                       uint32* __restrict__ D2bf, float* __restrict__ psi1,
                       float* __restrict__ psi2, float* __restrict__ xt,
                       float* __restrict__ h2z, float* __restrict__ outz) {
  __shared__ float smem[1056];
  int bid = blockIdx.x;
  const int tid = threadIdx.x;
  if (bid < 8192) {                       // cvt1: D1_to fp32 -> bf16 pad K1P
    const int total = 32000 * 896;
    for (int id = bid * 256 + tid; id < total; id += 8192 * 256) {
      const int r = id / 896, c2 = id % 896, cc = c2 * 2;
      const float* p = D1 + (size_t)r * NC1 + cc;
      const float lo = (cc < NC1) ? p[0] : 0.f;
      const float hi = (cc + 1 < NC1) ? p[1] : 0.f;
      D1bf[id] = pack_bf16(lo, hi);
    }
    return;
  }
  bid -= 8192;
  if (bid < 2048) {                       // cvt2: F1_from fp32 -> bf16
    const int total = 286 * 16000;
    for (int id = bid * 256 + tid; id < total; id += 2048 * 256) {
      F1bf[id] = pack_bf16(F1[2 * id], F1[2 * id + 1]);
    }
    return;
  }
  bid -= 2048;
  if (bid < 512) {                        // cvt3: D2_to fp32 -> bf16 pad K2P
    const int total = 6912 * 144;
    for (int id = bid * 256 + tid; id < total; id += 512 * 256) {
      const int r = id / 144, c2 = id % 144, cc = c2 * 2;
      const float* p = D2 + (size_t)r * NC2 + cc;
      const float lo = (cc < NC2) ? p[0] : 0.f;
      const float hi = (cc + 1 < NC2) ? p[1] : 0.f;
      D2bf[id] = pack_bf16(lo, hi);
    }
    return;
  }
  bid -= 512;
  if (bid < 800) {                        // psi2[i,j,c], blk = i*40+j
    float* w2s = smem;                    // 168
    if (tid < 168) w2s[tid] = w2[bid * 168 + tid];
    __syncthreads();
    for (int cc = tid; cc < NC2; cc += 256) {
      float s = 0.f;
      for (int n = 0; n < 168; ++n) s += Dk2[n * NC2 + cc] * w2s[n];
      psi2[bid * NC2 + cc] = s * RS168;
    }
    return;
  }
  bid -= 800;
  if (bid < 288) {                        // x transpose: 32x32 tiles
    float (*t)[33] = (float(*)[33])smem;  // 32*33 = 1056
    const int b = bid / 9, r9 = bid % 9, i0 = (r9 % 3) * 32, j0 = (r9 / 3) * 32;
    const int tx = tid & 31, ty0 = tid >> 5;
    const float* xb = x + b * 9216;
    float* xtb = xt + b * 9216;
#pragma unroll
    for (int r = 0; r < 4; ++r) {
      const int ty = ty0 + r * 8;
      t[ty][tx] = xb[(i0 + ty) * 96 + j0 + tx];
    }
    __syncthreads();
#pragma unroll
    for (int r = 0; r < 4; ++r) {
      const int ty = ty0 + r * 8;
      xtb[(j0 + ty) * 96 + i0 + tx] = t[tx][ty];
    }
    return;
  }
  bid -= 288;
  if (bid < 20) {                         // psi1[j,i]
    float* wsm = smem;                    // 24
    if (tid < 24) wsm[tid] = w1[bid * 24 + tid];
    __syncthreads();
    if (tid < 121) {
      float s = 0.f;
#pragma unroll
      for (int n = 0; n < 24; ++n) s += Yk1[n * 121 + tid] * wsm[n];
      psi1[bid * 121 + tid] = s * RS24;
    }
    return;
  }
  bid -= 20;
  {                                       // zero h2 (183040 f) + out (1280 f)
    int id = bid * 256 + tid;
    if (id < 45760) {
      ((float4*)h2z)[id] = make_float4(0.f, 0.f, 0.f, 0.f);
    } else {
      id -= 45760;
      if (id < 1280) outz[id] = 0.f;
    }
  }
}

// c[b,ch] = sum_g x_t[b,g] * from_s2[ch,g]  (coalesced float4)
__global__ void k_c2(const float* __restrict__ xt, const float* __restrict__ fs,
                     float* __restrict__ c) {
  const int ch = blockIdx.x, b = blockIdx.y, tid = threadIdx.x;
  const float4* xb = (const float4*)(xt + b * 9216);
  const float4* fr = (const float4*)(fs + ch * 9216);
  float s = 0.f;
#pragma unroll 3
  for (int g = tid; g < 2304; g += 256) {
    const float4 a = xb[g], d = fr[g];
    s += a.x * d.x + a.y * d.y + a.z * d.z + a.w * d.w;
  }
  s = wave_reduce(s);
  __shared__ float red[4];
  if ((tid & 63) == 0) red[tid >> 6] = s;
  __syncthreads();
  if (tid == 0) c[b * 121 + ch] = red[0] + red[1] + red[2] + red[3];
}

__global__ void k_h(const float* __restrict__ c, const float* __restrict__ psi1,
                    u16* __restrict__ hb) {
  const int j = blockIdx.x, b = blockIdx.y, tid = threadIdx.x;
  __shared__ float cs[121], ps[121];
  if (tid < 121) { cs[tid] = c[b * 121 + tid]; ps[tid] = psi1[j * 121 + tid]; }
  __syncthreads();
  for (int idx = tid; idx < K1P; idx += 256) {
    u16 v = 0;
    if (idx < NC1) {
      int off = 0, l = 0, k = 1;
      while (idx >= off + k * k) { off += k * k; ++l; k += 2; }
      const int r = idx - off, n = r / k, m = r % k;
      v = f2bf(cs[l * l + m] * ps[l * l + n]);
    }
    hb[(size_t)(b * F1_ + j) * K1P + idx] = v;
  }
}

// ------------------- GEMM1 v6: 2-wave blocks, wave tile 64x128 -------------
// g[m,n] = bf16( sqrt(2)*relu( sum_k hb[m,k] * D1bf[n,k] ) )
// M=640, N=32000, K=1792. Block tile 128x128, BK=32, 56 K-iters, triple LDS
// buffer (48 KB), vmcnt(8) gating, final stage vmcnt(0).
__launch_bounds__(128)
__global__ void k_gemm1_v6(const u16* __restrict__ A, const u16* __restrict__ B,
                           u16* __restrict__ C) {
  __shared__ __align__(16) u16 As0[128 * 32], As1[128 * 32], As2[128 * 32];
  __shared__ __align__(16) u16 Bs0[128 * 32], Bs1[128 * 32], Bs2[128 * 32];
  const int bid = blockIdx.x;                // 0..1249, XCD swizzle
  const int gg = bid / 40, loc = bid % 40;
  int nt, mt;
  if (gg < 31) { nt = gg * 8 + (loc & 7); mt = loc >> 3; }
  else         { nt = 248 + (loc & 1);   mt = loc >> 1; }
  const int m0 = mt * 128, n0 = nt * 128;
  const int tid = threadIdx.x;               // 128 threads = 2 waves
  const int lane = tid & 63, wm = tid >> 6;
  const int q = lane >> 4, r16 = lane & 15;

  const u16* ag = A + (size_t)(m0 + (tid >> 2)) * K1P + (tid & 3) * 8;
  const u16* bg = B + (size_t)(n0 + (tid >> 2)) * K1P + (tid & 3) * 8;

  // Per wave: 4 A-chunk + 4 B-chunk DMA (1 KB each). Rows (tid>>2)+i*32.
#define G1_ISSUE(kk, Asb, Bsb)                                                     \
  {                                                                                \
    _Pragma("unroll")                                                              \
    for (int i = 0; i < 4; ++i) {                                                  \
      __builtin_amdgcn_global_load_lds(AS1(ag + (kk) * 32 + (size_t)i * 32 * K1P), \
          AS3((char*)(Asb) + i * 2048 + wm * 1024), 16, 0, 0);                     \
      __builtin_amdgcn_global_load_lds(AS1(bg + (kk) * 32 + (size_t)i * 32 * K1P), \
          AS3((char*)(Bsb) + i * 2048 + wm * 1024), 16, 0, 0);                     \
    }                                                                              \
  }

#define G1_COMPUTE(Asb, Bsb)                                                       \
  {                                                                                \
    short8 af[4], bq[8];                                                           \
    _Pragma("unroll")                                                              \
    for (int mb = 0; mb < 4; ++mb)                                                 \
      af[mb] = *(const short8*)&(Asb)[(wm * 64 + mb * 16 + r16) * 32 + q * 8];     \
    _Pragma("unroll")                                                              \
    for (int nb = 0; nb < 8; ++nb)                                                 \
      bq[nb] = *(const short8*)&(Bsb)[(nb * 16 + r16) * 32 + q * 8];               \
    _Pragma("unroll")                                                              \
    for (int mb = 0; mb < 4; ++mb)                                                 \
      _Pragma("unroll")                                                            \
      for (int nb = 0; nb < 8; ++nb)                                               \
        acc[mb][nb] = __builtin_amdgcn_mfma_f32_16x16x32_bf16(af[mb], bq[nb],      \
                                                              acc[mb][nb], 0, 0, 0); \
  }

#define G1_STAGE(kk, wt, AsR, BsR, AsI, BsI)        \
  {                                                 \
    __builtin_amdgcn_s_waitcnt(wt);                 \
    __builtin_amdgcn_s_barrier();                   \
    asm volatile("" ::: "memory");                  \
    if ((kk) + 2 < 56) G1_ISSUE((kk) + 2, AsI, BsI) \
    G1_COMPUTE(AsR, BsR)                            \
  }

  f32x4 acc[4][8] = {};
  G1_ISSUE(0, As0, Bs0)
  G1_ISSUE(1, As1, Bs1)
  for (int k = 0; k < 54; k += 3) {
    G1_STAGE(k,     WAITCNT_VM8, As0, Bs0, As2, Bs2)
    G1_STAGE(k + 1, WAITCNT_VM8, As1, Bs1, As0, Bs0)
    G1_STAGE(k + 2, WAITCNT_VM8, As2, Bs2, As1, Bs1)
  }
  G1_STAGE(54, WAITCNT_VM8, As0, Bs0, As2, Bs2)
  G1_STAGE(55, WAITCNT_VM0, As1, Bs1, As0, Bs0)

#pragma unroll
  for (int mb = 0; mb < 4; ++mb) {
#pragma unroll
    for (int nb = 0; nb < 8; ++nb) {
      const int col = n0 + nb * 16 + r16;
#pragma unroll
      for (int r = 0; r < 4; ++r) {
        const int row = m0 + wm * 64 + mb * 16 + q * 4 + r;
        float v = acc[mb][nb][r];
        v = (v > 0.f) ? v * SQRT2_ : 0.f;
        C[(size_t)row * NG1 + col] = f2bf(v);
      }
    }
  }
#undef G1_ISSUE
#undef G1_COMPUTE
#undef G1_STAGE
}

// ------------------- GEMM2 (proven v3): split-K=20, LDS, syncthreads -------
__launch_bounds__(256)
__global__ void k_gemm2_v3(const u16* __restrict__ A, const u16* __restrict__ B,
                           float* __restrict__ C) {
  __shared__ __align__(16) u16 As[128 * 32];
  __shared__ __align__(16) u16 Bs[128 * 32];
  const int m0 = blockIdx.x * 128, n0 = blockIdx.y * 128;
  const int ks = blockIdx.z * 1600;
  const int tid = threadIdx.x;
  const int lane = tid & 63, w = tid >> 6;
  const int wm = w >> 1, wn = w & 1;
  const int q = lane >> 4, r16 = lane & 15;

  f32x4 acc[4][4] = {};
  const u16* ag = A + (size_t)(m0 + (tid >> 2)) * NG1 + ks + (tid & 3) * 8;
  int rb0 = n0 + (tid >> 2);        if (rb0 > 285) rb0 = 285;
  int rb1 = n0 + (tid >> 2) + 64;   if (rb1 > 285) rb1 = 285;
  const u16* bg0 = B + (size_t)rb0 * NG1 + ks + (tid & 3) * 8;
  const u16* bg1 = B + (size_t)rb1 * NG1 + ks + (tid & 3) * 8;

  for (int kt = 0; kt < 1600; kt += 32) {
#pragma unroll
    for (int i = 0; i < 2; ++i) {
      __builtin_amdgcn_global_load_lds(AS1(ag + kt + (size_t)i * 64 * NG1),
                                       AS3((char*)As + i * 4096 + w * 1024), 16, 0, 0);
    }
    __builtin_amdgcn_global_load_lds(AS1(bg0 + kt), AS3((char*)Bs + w * 1024), 16, 0, 0);
    __builtin_amdgcn_global_load_lds(AS1(bg1 + kt), AS3((char*)Bs + 4096 + w * 1024), 16, 0, 0);
    __syncthreads();
    short8 af[4], bq[4];
#pragma unroll
    for (int mb = 0; mb < 4; ++mb)
      af[mb] = *(const short8*)&As[(wm * 64 + mb * 16 + r16) * 32 + q * 8];
#pragma unroll
    for (int nb = 0; nb < 4; ++nb)
      bq[nb] = *(const short8*)&Bs[(wn * 64 + nb * 16 + r16) * 32 + q * 8];
#pragma unroll
    for (int mb = 0; mb < 4; ++mb)
#pragma unroll
      for (int nb = 0; nb < 4; ++nb)
        acc[mb][nb] = __builtin_amdgcn_mfma_f32_16x16x32_bf16(af[mb], bq[nb], acc[mb][nb], 0, 0, 0);
    __syncthreads();
  }
#pragma unroll
  for (int mb = 0; mb < 4; ++mb) {
#pragma unroll
    for (int nb = 0; nb < 4; ++nb) {
      const int col = n0 + wn * 64 + nb * 16 + r16;
      if (col < NC2) {
#pragma unroll
        for (int r = 0; r < 4; ++r) {
          const int row = m0 + wm * 64 + mb * 16 + q * 4 + r;
          atomicAdd(&C[(size_t)row * NC2 + col], acc[mb][nb][r]);
        }
      }
    }
  }
}

// GEMM3 fused epilogue: out[m] += sqrt(2)*sum_n relu(sum_k h3b[m,k]*D2bf[n,k])*F2_from[n]
__launch_bounds__(256)
__global__ void k_gemm3_v3(const u16* __restrict__ A, const u16* __restrict__ B,
                           const float* __restrict__ wv, float* __restrict__ out) {
  __shared__ __align__(16) u16 As[128 * 32];
  __shared__ __align__(16) u16 Bs[128 * 32];
  __shared__ float red[128][33];
  const int m0 = blockIdx.x * 128, n0 = blockIdx.y * 128;
  const int tid = threadIdx.x;
  const int lane = tid & 63, w = tid >> 6;
  const int wm = w >> 1, wn = w & 1;
  const int q = lane >> 4, r16 = lane & 15;

  f32x4 acc[4][4] = {};
  const u16* ag = A + (size_t)(m0 + (tid >> 2)) * K2P + (tid & 3) * 8;
  const u16* bg = B + (size_t)(n0 + (tid >> 2)) * K2P + (tid & 3) * 8;

  for (int k0 = 0; k0 < K2P; k0 += 32) {
#pragma unroll
    for (int i = 0; i < 2; ++i) {
      __builtin_amdgcn_global_load_lds(AS1(ag + k0 + (size_t)i * 64 * K2P),
                                       AS3((char*)As + i * 4096 + w * 1024), 16, 0, 0);
      __builtin_amdgcn_global_load_lds(AS1(bg + k0 + (size_t)i * 64 * K2P),
                                       AS3((char*)Bs + i * 4096 + w * 1024), 16, 0, 0);
    }
    __syncthreads();
    short8 af[4], bq[4];
#pragma unroll
    for (int mb = 0; mb < 4; ++mb)
      af[mb] = *(const short8*)&As[(wm * 64 + mb * 16 + r16) * 32 + q * 8];
#pragma unroll
    for (int nb = 0; nb < 4; ++nb)
      bq[nb] = *(const short8*)&Bs[(wn * 64 + nb * 16 + r16) * 32 + q * 8];
#pragma unroll
    for (int mb = 0; mb < 4; ++mb)
#pragma unroll
      for (int nb = 0; nb < 4; ++nb)
        acc[mb][nb] = __builtin_amdgcn_mfma_f32_16x16x32_bf16(af[mb], bq[nb], acc[mb][nb], 0, 0, 0);
    __syncthreads();
  }
  float wvv[4];
#pragma unroll
  for (int nb = 0; nb < 4; ++nb) wvv[nb] = wv[n0 + wn * 64 + nb * 16 + r16];
#pragma unroll
  for (int mb = 0; mb < 4; ++mb) {
#pragma unroll
    for (int r = 0; r < 4; ++r) {
      const int rowl = wm * 64 + mb * 16 + q * 4 + r;
      float t = 0.f;
#pragma unroll
      for (int nb = 0; nb < 4; ++nb) {
        float v = acc[mb][nb][r];
        v = (v > 0.f) ? v : 0.f;
        t += v * wvv[nb];
      }
      red[rowl][wn * 16 + r16] = t;
    }
  }
  __syncthreads();
  if (tid < 128) {
    float s = 0.f;
#pragma unroll
    for (int cc = 0; cc < 32; ++cc) s += red[tid][cc];
    atomicAdd(&out[m0 + tid], s * SQRT2_);
  }
}

// ------------------------- mid/tail kernels --------------------------------

__global__ void k_step7(const float* __restrict__ h2, const float* __restrict__ psi2,
                        u16* __restrict__ h3b) {
  const int j = blockIdx.x, b = blockIdx.y, tid = threadIdx.x;
  __shared__ float sh[20 * 286];
  __shared__ float sp[20 * 286];
  for (int e = tid; e < 20 * 286; e += 256) {
    const int i = e / 286, cc = e % 286;
    sh[e] = h2[(b * F1_ + i) * NC2 + cc];
    sp[e] = psi2[(i * F2_ + j) * NC2 + cc];
  }
  __syncthreads();
  for (int cidx = tid; cidx < K2P; cidx += 256) {
    u16 ov = 0;
    if (cidx < NC2) {
      int off = 0, l = 0, k = 1;
      while (cidx >= off + k * k) { off += k * k; ++l; k += 2; }
      const int r = cidx - off, v = r / k, m = r % k;
      float acc = 0.f;
      for (int i = 0; i < 20; ++i) {
        const float* hbp = &sh[i * 286 + off];
        const float* pb = &sp[i * 286 + off];
        for (int u = 0; u < k; ++u) acc += hbp[u * k + m] * pb[u * k + v];
      }
      ov = f2bf(acc * rsqrtf(20.f * (float)k));
    }
    h3b[(size_t)(b * F2_ + j) * K2P + cidx] = ov;
  }
}

// ------------------- fallback path kernels (ws too small) ------------------

__global__ void k_c(const float* __restrict__ x, const float* __restrict__ fs,
                    float* __restrict__ c) {
  const int ch = blockIdx.x, b = blockIdx.y, tid = threadIdx.x;
  const float* xb = x + b * 9216;
  const float* fr = fs + ch * 9216;
  float s = 0.f;
  for (int g = tid; g < 9216; g += 256) {
    s += xb[(g % 96) * 96 + (g / 96)] * fr[g];
  }
  s = wave_reduce(s);
  __shared__ float red[4];
  if ((tid & 63) == 0) red[tid >> 6] = s;
  __syncthreads();
  if (tid == 0) c[b * 121 + ch] = red[0] + red[1] + red[2] + red[3];
}

__global__ void k_psi1(const float* __restrict__ Yk1, const float* __restrict__ w1,
                       float* __restrict__ psi1) {
  const int j = blockIdx.x, i = threadIdx.x;
  __shared__ float wsm[24];
  if (i < 24) wsm[i] = w1[j * 24 + i];
  __syncthreads();
  if (i < 121) {
    float s = 0.f;
#pragma unroll
    for (int n = 0; n < 24; ++n) s += Yk1[n * 121 + i] * wsm[n];
    psi1[j * 121 + i] = s * RS24;
  }
}

__global__ void k_psi2(const float* __restrict__ Dk2, const float* __restrict__ w2,
                       float* __restrict__ psi2) {
  const int blk = blockIdx.x, tid = threadIdx.x;
  __shared__ float w2s[168];
  if (tid < 168) w2s[tid] = w2[blk * 168 + tid];
  __syncthreads();
  for (int cc = tid; cc < NC2; cc += 256) {
    float s = 0.f;
    for (int n = 0; n < 168; ++n) s += Dk2[n * NC2 + cc] * w2s[n];
    psi2[blk * NC2 + cc] = s * RS168;
  }
}

__global__ void k_cvt3(const float* __restrict__ in, uint32* __restrict__ out) {
  const int total = 6912 * 144;
  for (int id = blockIdx.x * 256 + threadIdx.x; id < total; id += gridDim.x * 256) {
    const int r = id / 144, c2 = id % 144, cc = c2 * 2;
    const float* p = in + (size_t)r * NC2 + cc;
    const float lo = (cc < NC2) ? p[0] : 0.f;
    const float hi = (cc + 1 < NC2) ? p[1] : 0.f;
    out[id] = pack_bf16(lo, hi);
  }
}

__launch_bounds__(256)
__global__ void k_gemm1_mfma(const u16* __restrict__ A, const float* __restrict__ Bf,
                             u16* __restrict__ C) {
  __shared__ __align__(16) u16 As[128 * 32];
  __shared__ __align__(16) u16 Bs[128 * 32];
  const int tid = threadIdx.x;
  const int lane = tid & 63, w = tid >> 6;
  const int wm = w >> 1, wn = w & 1;
  const int q = lane >> 4, r16 = lane & 15;
  const int m0 = blockIdx.x * 128, n0 = blockIdx.y * 128;

  f32x4 acc[4][4] = {};
  const u16* ag = A + (size_t)(m0 + (tid >> 2)) * K1P + (tid & 3) * 8;

  for (int k0 = 0; k0 < K1P; k0 += 32) {
#pragma unroll
    for (int i = 0; i < 2; ++i) {
      __builtin_amdgcn_global_load_lds(AS1(ag + k0 + (size_t)i * 64 * K1P),
                                       AS3((char*)As + i * 4096 + w * 1024), 16, 0, 0);
    }
#pragma unroll
    for (int i = 0; i < 8; ++i) {
      const int p = i * 256 + tid;
      const int row = p >> 4, c2 = (p & 15) * 2;
      const int kk = k0 + c2;
      const float* bpp = Bf + (size_t)(n0 + row) * NC1 + kk;
      const float lo = (kk < NC1) ? bpp[0] : 0.f;
      const float hi = (kk + 1 < NC1) ? bpp[1] : 0.f;
      ((uint32*)Bs)[row * 16 + (p & 15)] = pack_bf16(lo, hi);
    }
    __syncthreads();
    short8 af[4], bq[4];
#pragma unroll
    for (int mb = 0; mb < 4; ++mb)
      af[mb] = *(const short8*)&As[(wm * 64 + mb * 16 + r16) * 32 + q * 8];
#pragma unroll
    for (int nb = 0; nb < 4; ++nb)
      bq[nb] = *(const short8*)&Bs[(wn * 64 + nb * 16 + r16) * 32 + q * 8];
#pragma unroll
    for (int mb = 0; mb < 4; ++mb)
#pragma unroll
      for (int nb = 0; nb < 4; ++nb)
        acc[mb][nb] = __builtin_amdgcn_mfma_f32_16x16x32_bf16(af[mb], bq[nb], acc[mb][nb], 0, 0, 0);
    __syncthreads();
  }
#pragma unroll
  for (int mb = 0; mb < 4; ++mb) {
#pragma unroll
    for (int nb = 0; nb < 4; ++nb) {
      const int col = n0 + wn * 64 + nb * 16 + r16;
#pragma unroll
      for (int r = 0; r < 4; ++r) {
        const int row = m0 + wm * 64 + mb * 16 + q * 4 + r;
        float v = acc[mb][nb][r];
        v = (v > 0.f) ? v * SQRT2_ : 0.f;
        C[(size_t)row * NG1 + col] = f2bf(v);
      }
    }
  }
}

__launch_bounds__(256)
__global__ void k_gemm2_mfma(const u16* __restrict__ A, const float* __restrict__ Bf,
                             float* __restrict__ C) {
  __shared__ __align__(16) u16 As[128 * 32];
  __shared__ __align__(16) u16 Bs[128 * 32];
  const int tid = threadIdx.x;
  const int lane = tid & 63, w = tid >> 6;
  const int wm = w >> 1, wn = w & 1;
  const int q = lane >> 4, r16 = lane & 15;
  const int m0 = blockIdx.x * 128, n0 = blockIdx.y * 128;
  const int ks = blockIdx.z * 1600;

  f32x4 acc[4][4] = {};
  const u16* ag = A + (size_t)(m0 + (tid >> 2)) * NG1 + ks + (tid & 3) * 8;

  for (int kt = 0; kt < 1600; kt += 32) {
#pragma unroll
    for (int i = 0; i < 2; ++i) {
      __builtin_amdgcn_global_load_lds(AS1(ag + kt + (size_t)i * 64 * NG1),
                                       AS3((char*)As + i * 4096 + w * 1024), 16, 0, 0);
    }
#pragma unroll
    for (int i = 0; i < 4; ++i) {
      const int idx = i * 256 + tid;
      const int row = idx >> 3, c4 = (idx & 7) * 4;
      const int n = n0 + row;
      float4 v = make_float4(0.f, 0.f, 0.f, 0.f);
      if (n < NC2) v = *(const float4*)(Bf + (size_t)n * NG1 + ks + kt + c4);
      ((uint32*)Bs)[row * 16 + (idx & 7) * 2]     = pack_bf16(v.x, v.y);
      ((uint32*)Bs)[row * 16 + (idx & 7) * 2 + 1] = pack_bf16(v.z, v.w);
    }
    __syncthreads();
    short8 af[4], bq[4];
#pragma unroll
    for (int mb = 0; mb < 4; ++mb)
      af[mb] = *(const short8*)&As[(wm * 64 + mb * 16 + r16) * 32 + q * 8];
#pragma unroll
    for (int nb = 0; nb < 4; ++nb)
      bq[nb] = *(const short8*)&Bs[(wn * 64 + nb * 16 + r16) * 32 + q * 8];
#pragma unroll
    for (int mb = 0; mb < 4; ++mb)
#pragma unroll
      for (int nb = 0; nb < 4; ++nb)
        acc[mb][nb] = __builtin_amdgcn_mfma_f32_16x16x32_bf16(af[mb], bq[nb], acc[mb][nb], 0, 0, 0);
    __syncthreads();
  }
#pragma unroll
  for (int mb = 0; mb < 4; ++mb) {
#pragma unroll
    for (int nb = 0; nb < 4; ++nb) {
      const int col = n0 + wn * 64 + nb * 16 + r16;
      if (col < NC2) {
#pragma unroll
        for (int r = 0; r < 4; ++r) {
          const int row = m0 + wm * 64 + mb * 16 + q * 4 + r;
          atomicAdd(&C[(size_t)row * NC2 + col], acc[mb][nb][r]);
        }
      }
    }
  }
}

// ------------------------------- launcher ----------------------------------

extern "C" void kernel_launch(void* const* d_in, const int* in_sizes, int n_in,
                              void* d_out, int out_size, void* d_ws, size_t ws_size,
                              hipStream_t stream) {
  const float* x       = (const float*)d_in[0];
  const float* w1      = (const float*)d_in[1];
  const float* w2      = (const float*)d_in[2];
  const float* Yk1     = (const float*)d_in[3];
  const float* Dk2     = (const float*)d_in[4];
  const float* from_s2 = (const float*)d_in[5];
  const float* D1_to   = (const float*)d_in[6];
  const float* F1_from = (const float*)d_in[7];
  const float* D2_to   = (const float*)d_in[8];
  const float* F2_from = (const float*)d_in[9];
  float* out = (float*)d_out;

  float* ws = (float*)d_ws;
  float* c    = ws + 0;            //   3,872
  float* psi1 = ws + 3872;         //   2,420
  float* h2   = ws + 6292;         // 183,040 (16B-aligned offset)
  float* psi2 = ws + 189332;       // 228,800
  u16*   h3b  = (u16*)(ws + 418132);      // 1280*288 u16  = 184,320 f
  u16*   hb   = (u16*)(ws + 602452);      // 640*1792 u16  = 573,440 f
  u16*   g    = (u16*)(ws + 1175892);     // 640*32000 u16 = 10,240,000 f
  u16*   D2bf = (u16*)(ws + 11415892);    // 6912*288 u16  = 995,328 f
  u16*   F1bf = (u16*)(ws + 12411220);    // 286*32000 u16 = 4,576,000 f
  u16*   D1bf = (u16*)(ws + 16987220);    // 32000*1792 u16= 28,672,000 f
  float* x_t  = ws + 45659220;            // 32*9216       = 294,912 f
  const size_t NEED = (size_t)45954132 * 4;   // ~183.8 MB (proven OK R4/R5)
  const bool big = ws_size >= NEED;

  if (big) {
    k_prep<<<dim3(PREP_BLOCKS), 256, 0, stream>>>(
        D1_to, F1_from, D2_to, Yk1, w1, Dk2, w2, x,
        (uint32*)D1bf, (uint32*)F1bf, (uint32*)D2bf, psi1, psi2, x_t, h2, out);
    k_c2<<<dim3(121, 32), 256, 0, stream>>>(x_t, from_s2, c);
    k_h <<<dim3(20, 32),  256, 0, stream>>>(c, psi1, hb);
    k_gemm1_v6<<<dim3(1250), 128, 0, stream>>>(hb, D1bf, g);
    k_gemm2_v3<<<dim3(5, 3, 20), 256, 0, stream>>>(g, F1bf, h2);
    k_step7<<<dim3(40, 32), 256, 0, stream>>>(h2, psi2, h3b);
    k_gemm3_v3<<<dim3(10, 54), 256, 0, stream>>>(h3b, D2bf, F2_from, out);
  } else {
    k_c   <<<dim3(121, 32), 256, 0, stream>>>(x, from_s2, c);
    k_psi1<<<dim3(20),      128, 0, stream>>>(Yk1, w1, psi1);
    k_h   <<<dim3(20, 32),  256, 0, stream>>>(c, psi1, hb);
    k_cvt3<<<dim3(1024),    256, 0, stream>>>(D2_to, (uint32*)D2bf);
    k_gemm1_mfma<<<dim3(5, 250), 256, 0, stream>>>(hb, D1_to, g);
    hipMemsetAsync(h2, 0, (size_t)640 * 286 * sizeof(float), stream);
    k_gemm2_mfma<<<dim3(5, 3, 20), 256, 0, stream>>>(g, F1_from, h2);
    k_psi2 <<<dim3(800),    256, 0, stream>>>(Dk2, w2, psi2);
    k_step7<<<dim3(40, 32), 256, 0, stream>>>(h2, psi2, h3b);
    hipMemsetAsync(out, 0, (size_t)1280 * sizeof(float), stream);
    k_gemm3_v3<<<dim3(10, 54), 256, 0, stream>>>(h3b, D2bf, F2_from, out);
  }
}